// Round 1
// 90.566 us; speedup vs baseline: 1.0092x; 1.0092x over previous
//
#include <hip/hip_runtime.h>

// B=2, C=64, N=16384, K=16, C_OUT=64
// out[b,o,n] = relu( max_k( u[b,e1[b,n,k],o] + v[b,e0[b,n,k],o] ) + G[b,o] )
//   u = (W1-W2)-transform of x per node, v = W2-transform, G = W3*mean(x)+bias
//
// Workspace layout:
//   [0, 4Mi)          u : _Float16 [B][N][64]   (node-major: one node = 128B line)
//   [4Mi, 8Mi)        v : _Float16 [B][N][64]
//   [8Mi, +4KiB)      g_slots : float[8][128]   (partial column sums, atomic)
//   [8Mi+4Ki, +32KiB) ABg : float2[64][64]      AB[c][o] = {W1[o][c]-W2[o][c], W2[o][c]}

#define NNODES 16384
#define NCH 64

typedef _Float16 half8 __attribute__((ext_vector_type(8)));
typedef float f32x2 __attribute__((ext_vector_type(2)));

// ---------- K0: weight prep (once) + g_slots zero ----------
// 64 blocks x 64 threads; block o reads W row o coalesced, writes transposed
// AB column. Replaces the per-block strided W re-read in the old uv_kernel
// (1024 blocks x 2048 scattered line-touches each) with a one-time 32KB table.
__global__ __launch_bounds__(64) void prep_kernel(const float* __restrict__ W,
                                                  float2* __restrict__ ABg,
                                                  float* __restrict__ g_slots) {
  int o = blockIdx.x;   // 0..63
  int t = threadIdx.x;  // 0..63 = input channel c
  if (o == 0) {
#pragma unroll
    for (int i = 0; i < 16; ++i) g_slots[t + i * 64] = 0.0f;
  }
  float w1 = W[o * 192 + t];
  float w2 = W[o * 192 + 64 + t];
  ABg[t * 64 + o] = make_float2(w1 - w2, w2);
}

// ---------- K1: u/v node transform + x column-sum ----------
// grid = B * (N/64) = 512 blocks, 256 threads (4 waves), wave handles 16 nodes,
// lanes over output channel o.
// KEY CHANGE vs previous version: x is staged into LDS with COALESCED per-lane
// vector loads (the old wave-uniform float4 reads at 64KB stride hammered the
// scalar-memory miss path). Main loop reads x as wave-uniform ds_read_b128
// (LDS broadcast, conflict-free) and weights as ds_read_b64 (2-way, free).
// Column sums are computed from the staging registers via 16-lane shuffle
// reduce -- the global re-read pass is gone.
__global__ __launch_bounds__(256) void uv_kernel(const float* __restrict__ x,
                                                 const float2* __restrict__ ABg,
                                                 _Float16* __restrict__ u,
                                                 _Float16* __restrict__ v,
                                                 float* __restrict__ g_slots) {
  __shared__ float2 ABs[64 * 64];  // [c][o]  32 KB
  __shared__ float xs[64][64];     // [c][node] 16 KB (256B rows, 16B aligned)
  __shared__ float csumS[64];
  int t = threadIdx.x;
  int lane = t & 63;
  int wv = __builtin_amdgcn_readfirstlane(t >> 6);
  int blk = blockIdx.x;        // 0..511
  int b = blk >> 8;            // 256 blocks per batch
  int mb = (blk & 255) * 64;   // block's 64 nodes

  // ---- stage AB: linear coalesced 32KB copy (L2-hot after first blocks) ----
  {
    const float4* src = (const float4*)ABg;
    float4* dst = (float4*)ABs;
#pragma unroll
    for (int j = 0; j < 8; ++j) dst[t + j * 256] = src[t + j * 256];
  }
  // ---- stage x slice [64ch][64nodes] with coalesced float4 vector loads ----
  {
    const float* xb = x + (size_t)b * (NCH * NNODES) + mb;
    int off = t & 15;  // node-quad within row
#pragma unroll
    for (int j = 0; j < 4; ++j) {
      int c = (t >> 4) + j * 16;
      float4 q = *(const float4*)(xb + (size_t)c * NNODES + off * 4);
      *(float4*)&xs[c][off * 4] = q;
      // column-sum: 16 lanes (same c, different node-quads) shuffle-reduce
      float s = (q.x + q.y) + (q.z + q.w);
      s += __shfl_xor(s, 1, 16);
      s += __shfl_xor(s, 2, 16);
      s += __shfl_xor(s, 4, 16);
      s += __shfl_xor(s, 8, 16);
      if (off == 0) csumS[c] = s;
    }
  }
  __syncthreads();
  if (t < 64) atomicAdd(&g_slots[((blk & 7) << 7) + b * 64 + t], csumS[t]);

  // ---- main transform: wave's 16 nodes, lane = output channel ----
  int m0 = wv * 16;
  f32x2 aU[8], aV[8];
#pragma unroll
  for (int i = 0; i < 8; ++i) {
    aU[i] = (f32x2){0.f, 0.f};
    aV[i] = (f32x2){0.f, 0.f};
  }
#pragma unroll 8
  for (int c = 0; c < 64; ++c) {
    float2 ab = ABs[c * 64 + lane];   // ds_read_b64, 2-way (free)
    f32x2 a2 = {ab.x, ab.x};
    f32x2 b2 = {ab.y, ab.y};
    const float4* xr = (const float4*)&xs[c][m0];  // uniform -> broadcast
    float4 q0 = xr[0];
    float4 q1 = xr[1];
    float4 q2 = xr[2];
    float4 q3 = xr[3];
    f32x2 p0 = {q0.x, q0.y}, p1 = {q0.z, q0.w};
    f32x2 p2 = {q1.x, q1.y}, p3 = {q1.z, q1.w};
    f32x2 p4 = {q2.x, q2.y}, p5 = {q2.z, q2.w};
    f32x2 p6 = {q3.x, q3.y}, p7 = {q3.z, q3.w};
    aU[0] = __builtin_elementwise_fma(a2, p0, aU[0]);
    aU[1] = __builtin_elementwise_fma(a2, p1, aU[1]);
    aU[2] = __builtin_elementwise_fma(a2, p2, aU[2]);
    aU[3] = __builtin_elementwise_fma(a2, p3, aU[3]);
    aU[4] = __builtin_elementwise_fma(a2, p4, aU[4]);
    aU[5] = __builtin_elementwise_fma(a2, p5, aU[5]);
    aU[6] = __builtin_elementwise_fma(a2, p6, aU[6]);
    aU[7] = __builtin_elementwise_fma(a2, p7, aU[7]);
    aV[0] = __builtin_elementwise_fma(b2, p0, aV[0]);
    aV[1] = __builtin_elementwise_fma(b2, p1, aV[1]);
    aV[2] = __builtin_elementwise_fma(b2, p2, aV[2]);
    aV[3] = __builtin_elementwise_fma(b2, p3, aV[3]);
    aV[4] = __builtin_elementwise_fma(b2, p4, aV[4]);
    aV[5] = __builtin_elementwise_fma(b2, p5, aV[5]);
    aV[6] = __builtin_elementwise_fma(b2, p6, aV[6]);
    aV[7] = __builtin_elementwise_fma(b2, p7, aV[7]);
  }
  // ---- store u/v fp16; each store inst = 64 lanes x 2B = one 128B line ----
  _Float16* ub = u + ((size_t)b * NNODES + mb + m0) * NCH + lane;
  _Float16* vb = v + ((size_t)b * NNODES + mb + m0) * NCH + lane;
#pragma unroll
  for (int i = 0; i < 8; ++i) {
    ub[(2 * i) * NCH] = (_Float16)aU[i][0];
    ub[(2 * i + 1) * NCH] = (_Float16)aU[i][1];
    vb[(2 * i) * NCH] = (_Float16)aV[i][0];
    vb[(2 * i + 1) * NCH] = (_Float16)aV[i][1];
  }
}

// ---------- K2: G + gather + max + relu, transpose to [b][o][n] ----------
// grid = B * (N/32) = 1024 blocks, 256 threads (4 waves).
// Wave covers 8 nodes: 8 lanes/node, each lane owns 8 channels (half8 = 16B
// loads; a node's 64 fp16 = one aligned 128B line).
// Changes vs previous: gather loop split into two 8-deep load batches (16
// in-flight loads instead of 32 -> lower VGPR, better occupancy), dual max
// accumulator chains (halves the serial v_pk_max dependency), and 32-bit byte
// offsets so loads use the sgpr-base + u32-voffset form.
// XCD swizzle: blockIdx%8 is the XCD; XCDs 0-3 -> batch 0, 4-7 -> batch 1 so
// each XCD's gather working set (u_b+v_b = 4MB) fits its private 4MB L2.
__global__ __launch_bounds__(256) void gather_kernel(const int* __restrict__ ei,
                                                     const _Float16* __restrict__ u,
                                                     const _Float16* __restrict__ v,
                                                     const float* __restrict__ W,
                                                     const float* __restrict__ bias,
                                                     const float* __restrict__ g_slots,
                                                     float* __restrict__ out) {
  __shared__ float tile[64][33];
  __shared__ float gb[64];
  __shared__ float pg[4][64];
  __shared__ float G_s[64];
  int t = threadIdx.x;
  int lane = t & 63;
  int wv = t >> 6;                      // 0..3
  int blk = blockIdx.x;                 // 0..1023
  int xcd = blk & 7;
  int b = xcd >> 2;                     // batch pinned to XCD group
  int nb = (blk >> 3) * 4 + (xcd & 3);  // 0..511
  int n0 = nb * 32;                     // block's 32 nodes
  int q = lane >> 3;                    // node within wave 0..7
  int r = lane & 7;                     // channel-octet 0..7
  const int* e0b = ei + (size_t)b * NNODES * 16;        // edge_index[0][b]
  const int* e1b = ei + (size_t)(2 + b) * NNODES * 16;  // edge_index[1][b]
  // Index preload: lane (q,r) holds k=r and k=r+8 for its node q.
  int f0 = (n0 + wv * 8) * 16 + q * 16 + r;
  int i0a = e0b[f0];
  int i0b = e0b[f0 + 8];
  int i1a = e1b[f0];
  int i1b = e1b[f0 + 8];
  // ---- fused G = W3*(colsum/N) + bias (overlaps the index-load latency) ----
  if (t < 64) {
    float s = 0.f;
#pragma unroll
    for (int sl = 0; sl < 8; ++sl) s += g_slots[sl * 128 + b * 64 + t];
    gb[t] = s * (1.0f / 16384.0f);
  }
  __syncthreads();
  {
    int o = t >> 2, cq = t & 3;
    const float4* wr = (const float4*)(W + o * 192 + 128 + cq * 16);
    const float4* gr = (const float4*)(gb + cq * 16);
    float s = 0.f;
#pragma unroll
    for (int j = 0; j < 4; ++j) {
      float4 w = wr[j];
      float4 gg = gr[j];
      s += w.x * gg.x + w.y * gg.y + w.z * gg.z + w.w * gg.w;
    }
    pg[cq][o] = s;
  }
  __syncthreads();
  if (t < 64) G_s[t] = bias[t] + ((pg[0][t] + pg[1][t]) + (pg[2][t] + pg[3][t]));
  __syncthreads();
  // ---- gather + running max (two 8-deep batches, dual max chains) ----
  const char* ubase = (const char*)(u + (size_t)b * NNODES * NCH);
  const char* vbase = (const char*)(v + (size_t)b * NNODES * NCH);
  uint32_t r16 = (uint32_t)(r * 16);
  half8 accA, accB;
#pragma unroll
  for (int j = 0; j < 8; ++j) {
    accA[j] = (_Float16)(-60000.0f);
    accB[j] = (_Float16)(-60000.0f);
  }
#pragma unroll
  for (int h = 0; h < 2; ++h) {
    half8 ua[8], va[8];
#pragma unroll
    for (int k = 0; k < 8; ++k) {
      int src = (lane & 56) + k;                  // lane holding (my node q, k)
      int m1 = __shfl(h ? i1b : i1a, src, 64);    // h resolved at compile time
      int m0i = __shfl(h ? i0b : i0a, src, 64);
      ua[k] = *(const half8*)(ubase + ((uint32_t)m1 * 128u + r16));
      va[k] = *(const half8*)(vbase + ((uint32_t)m0i * 128u + r16));
    }
#pragma unroll
    for (int k = 0; k < 8; ++k) {
      half8 s = ua[k] + va[k];                    // v_pk_add_f16 x4
      if (k & 1)
        accB = __builtin_elementwise_max(accB, s);
      else
        accA = __builtin_elementwise_max(accA, s);
    }
  }
  half8 acc = __builtin_elementwise_max(accA, accB);
  // ---- epilogue: +G, relu, LDS transpose ----
  int col = wv * 8 + q;  // node column 0..31
#pragma unroll
  for (int j = 0; j < 8; ++j) {
    tile[r * 8 + j][col] = fmaxf((float)acc[j] + G_s[r * 8 + j], 0.0f);
  }
  __syncthreads();
#pragma unroll
  for (int j = 0; j < 8; ++j) {
    int o = (t >> 5) + j * 8;
    int c2 = t & 31;
    out[((size_t)b * 64 + o) * NNODES + n0 + c2] = tile[o][c2];
  }
}

extern "C" void kernel_launch(void* const* d_in, const int* in_sizes, int n_in,
                              void* d_out, int out_size, void* d_ws, size_t ws_size,
                              hipStream_t stream) {
  const float* x = (const float*)d_in[0];
  const int* ei = (const int*)d_in[1];
  const float* W = (const float*)d_in[2];
  const float* bias = (const float*)d_in[3];
  float* out = (float*)d_out;

  char* ws = (char*)d_ws;
  _Float16* u = (_Float16*)ws;                               // 4 MiB
  _Float16* v = (_Float16*)(ws + (size_t)4 * 1024 * 1024);   // 4 MiB
  float* g_slots = (float*)(ws + (size_t)8 * 1024 * 1024);   // 8*128 floats
  float2* ABg = (float2*)(ws + (size_t)8 * 1024 * 1024 + 4096);  // 32 KiB

  prep_kernel<<<64, 64, 0, stream>>>(W, ABg, g_slots);
  uv_kernel<<<512, 256, 0, stream>>>(x, ABg, u, v, g_slots);
  gather_kernel<<<1024, 256, 0, stream>>>(ei, u, v, W, bias, g_slots, out);
}